// Round 4
// baseline (763.463 us; speedup 1.0000x reference)
//
#include <hip/hip_runtime.h>
#include <hip/hip_bf16.h>
#include <math.h>

typedef __hip_bfloat16 bf16;
typedef __attribute__((ext_vector_type(8))) short short8;
typedef __attribute__((ext_vector_type(4))) float floatx4;
typedef unsigned int u32;

#define NTOK 147456
#define IMG 384

__device__ __forceinline__ int gather_row(int m) {
    int gw = m >> 6, t = m & 63;
    int wr = gw / 48, wc = gw - wr * 48;
    int hh = wr * 8 + (t >> 3);
    int ww = wc * 8 + (t & 7);
    int oh = hh + 4; if (oh >= IMG) oh -= IMG;
    int ow = ww + 4; if (ow >= IMG) ow -= IMG;
    return oh * IMG + ow;
}

__device__ __forceinline__ unsigned short f2bu(float f) {
    unsigned u = __float_as_uint(f);
    unsigned r = (u + 0x7fffu + ((u >> 16) & 1u)) >> 16;   // RNE
    return (unsigned short)r;
}
__device__ __forceinline__ float bu2f(unsigned short u) {
    return __uint_as_float(((unsigned)u) << 16);
}

// HW packed f32->bf16 RNE conversion (same bits as f2bu)
__device__ __forceinline__ u32 cvt_pk_bf16(float lo, float hi) {
    u32 r;
    asm("v_cvt_pk_bf16_f32 %0, %1, %2" : "=v"(r) : "v"(lo), "v"(hi));
    return r;
}

// fast exact-GELU: 0.5*x*(1+erf(x/sqrt2)); erf via A&S 7.1.26, |err|<1.5e-7
__device__ __forceinline__ float gelu_fast(float x) {
    const float z = fabsf(x) * 0.70710678118654752f;
    const float t = __builtin_amdgcn_rcpf(fmaf(0.3275911f, z, 1.0f));
    float p = fmaf(1.061405429f, t, -1.453152027f);
    p = fmaf(p, t, 1.421413741f);
    p = fmaf(p, t, -0.284496736f);
    p = fmaf(p, t, 0.254829592f);
    p *= t;
    const float e = __expf(-z * z);
    float erfv = fmaf(-p, e, 1.0f);
    erfv = (x < 0.0f) ? -erfv : erfv;
    return 0.5f * x * (1.0f + erfv);
}

// ---------------- prep kernels ----------------

// hidden fp32 -> bf16 A-frag-packed, gathered window order: [mtG][kg24][m16][8]
__global__ __launch_bounds__(256)
void conv_pack(const float* __restrict__ hidden, bf16* __restrict__ Apk)
{
    const int cid = blockIdx.x * 256 + threadIdx.x;    // < 9216*24*16
    const int mtG = cid / 384;
    const int rest = cid - mtG * 384;
    const int kg = rest >> 4, mm = rest & 15;
    const int tok = mtG * 16 + mm;
    const float* p = hidden + (size_t)gather_row(tok) * 192 + kg * 8;
    const float4 a = *(const float4*)p;
    const float4 b = *(const float4*)(p + 4);
    short8 o;
    o[0] = (short)f2bu(a.x); o[1] = (short)f2bu(a.y);
    o[2] = (short)f2bu(a.z); o[3] = (short)f2bu(a.w);
    o[4] = (short)f2bu(b.x); o[5] = (short)f2bu(b.y);
    o[6] = (short)f2bu(b.z); o[7] = (short)f2bu(b.w);
    *(short8*)(Apk + (size_t)cid * 8) = o;
}

// W fp32 [K][N] row-major -> bf16 B-frag-packed [ntG][kg][n16][8]
__global__ __launch_bounds__(256)
void pack_w(const float* __restrict__ W, bf16* __restrict__ out, int K, int N)
{
    const int cid = blockIdx.x * 256 + threadIdx.x;
    const int KG = K >> 3;
    const int total = (N >> 4) * KG * 16;
    if (cid >= total) return;
    const int n = cid & 15;
    const int kg = (cid >> 4) % KG;
    const int ntG = (cid >> 4) / KG;
    short8 o;
#pragma unroll
    for (int j = 0; j < 8; ++j)
        o[j] = (short)f2bu(W[(size_t)(kg * 8 + j) * N + ntG * 16 + n]);
    *(short8*)(out + (size_t)cid * 8) = o;
}

__global__ __launch_bounds__(256)
void fuse_bias(const float* __restrict__ qb, const float* __restrict__ vb,
               float* __restrict__ out)
{
    const int t = blockIdx.x * 256 + threadIdx.x;
    if (t >= 576) return;
    out[t] = (t < 192) ? qb[t] : ((t < 384) ? 0.0f : vb[t - 384]);
}

// ---------------- MFMA GEMM ----------------
#define EPI_NONE 0
#define EPI_GELU 1

// Barrier-free design: A-frags in registers (packed layout == fragment
// layout); B-frags read DIRECTLY from global per MFMA — each frag is a
// contiguous, coalesced 1 KiB wave read, L1/L2-resident (B <= 442 KB, and
// all 4 waves of a block read the same frags). No LDS staging, no
// s_barrier, no vmcnt choreography: pure dataflow, compiler pipelines
// loads across the fully-unrolled K loop. Epilogue transpose uses a
// wave-private LDS slab (no cross-wave sync).
template<int KDIM, bool PACK_OUT, int EPI, int KGOUT, int MW>
__global__ __launch_bounds__(256, MW)
void gemm_mfma(const bf16* __restrict__ Apk, const bf16* __restrict__ Bpk,
               const float* __restrict__ bias, bf16* __restrict__ C, int N)
{
    constexpr int KG = KDIM / 8;     // k-groups of 8
    constexpr int KT = KDIM / 32;    // 32-wide k tiles
    __shared__ __align__(16) char wbs[4][4608];   // per-wave transpose buf
    const int wave = threadIdx.x >> 6, lane = threadIdx.x & 63;
    const int bm = blockIdx.x * 128;
    const int NPo = N / 64;
    const char* Bsrc = (const char*)Bpk;
    char* wb = wbs[wave];

    // ---- A-frags -> registers, once per block ----
    short8 areg[2][KT];
    {
        const char* Asrc = (const char*)Apk;
#pragma unroll
        for (int x = 0; x < 2; ++x) {
            const size_t rowb = (size_t)((bm >> 4) + wave * 2 + x) * KG * 256;
#pragma unroll
            for (int kt = 0; kt < KT; ++kt)
                areg[x][kt] = *(const short8*)(Asrc + rowb + (size_t)kt * 1024 + lane * 16);
        }
    }

    for (int npo = 0; npo < NPo; ++npo) {
        floatx4 acc[8];
#pragma unroll
        for (int f = 0; f < 8; ++f)
            acc[f] = (floatx4){0.f, 0.f, 0.f, 0.f};

        const char* bbase = Bsrc + (size_t)npo * 4 * KG * 256 + lane * 16;
#pragma unroll
        for (int kt = 0; kt < KT; ++kt) {
            const short8 a0 = areg[0][kt];
            const short8 a1 = areg[1][kt];
#pragma unroll
            for (int nt = 0; nt < 4; ++nt) {
                const short8 b = *(const short8*)(bbase + (size_t)(nt * KG + kt * 4) * 256);
                acc[nt]     = __builtin_amdgcn_mfma_f32_16x16x32_bf16(a0, b, acc[nt],     0, 0, 0);
                acc[4 + nt] = __builtin_amdgcn_mfma_f32_16x16x32_bf16(a1, b, acc[4 + nt], 0, 0, 0);
            }
        }

        // ---- epilogue: bias (+gelu), bf16, wave-private LDS transpose ----
#pragma unroll
        for (int m2 = 0; m2 < 2; ++m2) {
#pragma unroll
            for (int nt = 0; nt < 4; ++nt) {
                const floatx4 v = acc[m2 * 4 + nt];
                const int c = nt * 16 + (lane & 15);
                const float bval = bias ? bias[npo * 64 + c] : 0.0f;
#pragma unroll
                for (int i = 0; i < 4; ++i) {
                    float f = v[i] + bval;
                    if (EPI == EPI_GELU)
                        f = gelu_fast(f);
                    const int r = m2 * 16 + (lane >> 4) * 4 + i;
                    *(unsigned short*)(wb + (r * 72 + c) * 2) = f2bu(f);
                }
            }
        }
        // same-wave RAW on wb: compiler inserts the lgkmcnt wait
        if (PACK_OUT) {
            const int m = lane >> 1, c2 = (lane & 1) * 32;
            const int grow = bm + wave * 32 + m;
#pragma unroll
            for (int i = 0; i < 4; ++i) {
                const short8 row = *(const short8*)(wb + (m * 72 + c2 + i * 8) * 2);
                const int gcol = npo * 64 + c2 + i * 8;
                bf16* dst = C + ((size_t)((grow >> 4) * KGOUT + (gcol >> 3)) * 16 + (grow & 15)) * 8;
                *(short8*)dst = row;
            }
        } else {
            // full-128B-line stores: 8 lanes cover one row segment per issue
            const int mr = lane >> 3, c2 = (lane & 7) * 8;
#pragma unroll
            for (int i = 0; i < 4; ++i) {
                const int rr = i * 8 + mr;
                const short8 row = *(const short8*)(wb + (rr * 72 + c2) * 2);
                bf16* dst = C + (size_t)(bm + wave * 32 + rr) * N + npo * 64 + c2;
                *(short8*)dst = row;
            }
        }
    }
}

// ---------------- CPB MLP + RPB ----------------

__device__ __forceinline__ float cpb_coord(int i) {
    float a = (float)(i - 7) * (8.0f / 7.0f);
    float s = (a > 0.f) ? 1.f : ((a < 0.f) ? -1.f : 0.f);
    return s * log2f(fabsf(a) + 1.0f) * (1.0f / 3.0f);
}

__global__ __launch_bounds__(512)
void cpb_mlp(const float* __restrict__ w1, const float* __restrict__ b1,
             const float* __restrict__ w2, float* __restrict__ tab)
{
    const int r = blockIdx.x;
    const int t = threadIdx.x;
    const float x0 = cpb_coord(r / 15);
    const float x1 = cpb_coord(r % 15);
    const float hgt = fmaxf(x0 * w1[t] + x1 * w1[512 + t] + b1[t], 0.0f);
    __shared__ float red[512];
    for (int n = 0; n < 6; ++n) {
        red[t] = hgt * w2[t * 6 + n];
        __syncthreads();
        for (int s = 256; s > 0; s >>= 1) {
            if (t < s) red[t] += red[t + s];
            __syncthreads();
        }
        if (t == 0) tab[r * 6 + n] = red[0];
        __syncthreads();
    }
}

// rpb' = 16*sigmoid(v) - (scale_h + 16): folds the softmax constant-shift C
// so attn can do exp(S*scale + rpb') directly (no row-max pass).
__global__ __launch_bounds__(256)
void rpb_expand(const float* __restrict__ tab, const float* __restrict__ logit_scale,
                float* __restrict__ rpb)
{
    const int idx = blockIdx.x * 256 + threadIdx.x;
    if (idx >= 6 * 4096) return;
    const int h = idx >> 12;
    const int t = (idx >> 6) & 63;
    const int j = idx & 63;
    const int pr = t >> 3, pc = t & 7, qr = j >> 3, qc = j & 7;
    const int ridx = (pr - qr + 7) * 15 + (pc - qc + 7);
    const float v = tab[ridx * 6 + h];
    const float scale = __expf(fminf(logit_scale[h], 4.6051701859880914f));
    rpb[idx] = 16.0f / (1.0f + expf(-v)) - scale - 16.0f;
}

// ---------------- MFMA attention ----------------
// one wave per (window, head); 4 waves/block; all LDS wave-private (no barriers).
// Raw bf16 Q/K frags feed QK^T directly; cosine norms applied to the f32
// accumulator (rnk lane-local, rnq via 16 shfls). Softmax uses a constant
// shift C=scale+16 (pre-folded into rpb) instead of a row-max pass.
__global__ __launch_bounds__(256, 2)
void attn_mfma(const bf16* __restrict__ QKV, const float* __restrict__ rpb,
               const float* __restrict__ logit_scale, bf16* __restrict__ Ctx)
{
    __shared__ __align__(16) char lds[4][9216];
    const int wave = threadIdx.x >> 6, lane = threadIdx.x & 63;
    const int l15 = lane & 15, quad = lane >> 4;
    const int wh = blockIdx.x * 4 + wave;
    const int w = wh / 6, h = wh - w * 6;
    char* Pb = lds[wave];            // 64 rows x 36 bf16 (P halves, then ctx)
    char* Vt = lds[wave] + 4608;     // 32 rows x 72 bf16 (V transposed)

    const bf16* wbase = QKV + (size_t)w * 64 * 576;

    // ---- stage V^T: lane = token, writes its column (2 lanes/bank: free) ----
    {
        const bf16* vp = wbase + (size_t)lane * 576 + 384 + h * 32;
        const short8 v0 = *(const short8*)(vp);
        const short8 v1 = *(const short8*)(vp + 8);
        const short8 v2 = *(const short8*)(vp + 16);
        const short8 v3 = *(const short8*)(vp + 24);
#pragma unroll
        for (int j = 0; j < 8; ++j) {
            *(short*)(Vt + ((j     ) * 72 + lane) * 2) = v0[j];
            *(short*)(Vt + ((j +  8) * 72 + lane) * 2) = v1[j];
            *(short*)(Vt + ((j + 16) * 72 + lane) * 2) = v2[j];
            *(short*)(Vt + ((j + 24) * 72 + lane) * 2) = v3[j];
        }
    }

    // ---- region ids (mask only matters on last window row/col) ----
    const int wr = w / 48, wc = w - wr * 48;
    const bool edge = (wr == 47) || (wc == 47);
    int rid_j[4];
    if (edge) {
#pragma unroll
        for (int jt = 0; jt < 4; ++jt) {
            const int t = jt * 16 + l15;
            const int rr = (wr == 47) ? (((t >> 3) < 4) ? 1 : 2) : 0;
            const int rc = (wc == 47) ? (((t & 7) < 4) ? 1 : 2) : 0;
            rid_j[jt] = rr * 3 + rc;
        }
    }

    const float scale = __expf(fminf(logit_scale[h], 4.6051701859880914f));

    // ---- K frags (raw bf16) + per-col inverse norms ----
    short8 kfr[4];
    float rnk[4];
#pragma unroll
    for (int jt = 0; jt < 4; ++jt) {
        kfr[jt] = *(const short8*)(wbase + (size_t)(jt * 16 + l15) * 576 + 192 + h * 32 + quad * 8);
        float ss = 0.f;
#pragma unroll
        for (int j = 0; j < 8; ++j) {
            const float f = bu2f((unsigned short)kfr[jt][j]);
            ss = fmaf(f, f, ss);
        }
        ss += __shfl_xor(ss, 16); ss += __shfl_xor(ss, 32);
        rnk[jt] = __builtin_amdgcn_rcpf(fmaxf(__builtin_amdgcn_sqrtf(ss), 1e-12f));
    }

    // ---- S = Q K^T on raw frags; per-row inverse norms (scale folded) ----
    floatx4 acc[4][4];
    float rnq[4];
#pragma unroll
    for (int it = 0; it < 4; ++it)
#pragma unroll
        for (int jt = 0; jt < 4; ++jt)
            acc[it][jt] = (floatx4){0.f, 0.f, 0.f, 0.f};
#pragma unroll
    for (int it = 0; it < 4; ++it) {
        const short8 qf = *(const short8*)(wbase + (size_t)(it * 16 + l15) * 576 + h * 32 + quad * 8);
        float ss = 0.f;
#pragma unroll
        for (int j = 0; j < 8; ++j) {
            const float f = bu2f((unsigned short)qf[j]);
            ss = fmaf(f, f, ss);
        }
        ss += __shfl_xor(ss, 16); ss += __shfl_xor(ss, 32);
        rnq[it] = scale * __builtin_amdgcn_rcpf(fmaxf(__builtin_amdgcn_sqrtf(ss), 1e-12f));
#pragma unroll
        for (int jt = 0; jt < 4; ++jt)
            acc[it][jt] = __builtin_amdgcn_mfma_f32_16x16x32_bf16(qf, kfr[jt], acc[it][jt], 0, 0, 0);
    }

    const float* rpbh = rpb + h * 4096;   // already has -(scale+16) folded in

    // ---- normalize + bias + mask + exp + row-sum (no max pass) ----
    float inv[4][4];
#pragma unroll
    for (int it = 0; it < 4; ++it) {
#pragma unroll
        for (int r = 0; r < 4; ++r) {
            const int i = it * 16 + quad * 4 + r;
            const float rq = __shfl(rnq[it], quad * 4 + r);
            int rid_i = 0;
            if (edge) {
                const int rr = (wr == 47) ? (((i >> 3) < 4) ? 1 : 2) : 0;
                const int rc = (wc == 47) ? (((i & 7) < 4) ? 1 : 2) : 0;
                rid_i = rr * 3 + rc;
            }
            float s = 0.f;
#pragma unroll
            for (int jt = 0; jt < 4; ++jt) {
                float v = fmaf(acc[it][jt][r], rq * rnk[jt], rpbh[i * 64 + jt * 16 + l15]);
                if (edge && rid_i != rid_j[jt]) v -= 200.0f;   // mask added twice in ref
                const float e = __expf(v);
                acc[it][jt][r] = e; s += e;
            }
            s += __shfl_xor(s, 1); s += __shfl_xor(s, 2);
            s += __shfl_xor(s, 4); s += __shfl_xor(s, 8);
            inv[it][r] = __builtin_amdgcn_rcpf(s);
        }
    }

    // ---- ctx = P V via LDS round-trip in two 32-key halves ----
    floatx4 ctx[4][2];
#pragma unroll
    for (int it = 0; it < 4; ++it)
#pragma unroll
        for (int dt = 0; dt < 2; ++dt)
            ctx[it][dt] = (floatx4){0.f, 0.f, 0.f, 0.f};

#pragma unroll
    for (int ks = 0; ks < 2; ++ks) {
#pragma unroll
        for (int it = 0; it < 4; ++it)
#pragma unroll
            for (int r = 0; r < 4; ++r) {
                const int i = it * 16 + quad * 4 + r;
                const u32 pk = cvt_pk_bf16(acc[it][ks * 2][r], acc[it][ks * 2 + 1][r]);
                *(short*)(Pb + (i * 36 + l15) * 2)      = (short)pk;
                *(short*)(Pb + (i * 36 + 16 + l15) * 2) = (short)(pk >> 16);
            }
#pragma unroll
        for (int it = 0; it < 4; ++it) {
            const short8 pf = *(const short8*)(Pb + ((it * 16 + l15) * 36 + quad * 8) * 2);
#pragma unroll
            for (int dt = 0; dt < 2; ++dt) {
                const short8 vf = *(const short8*)(Vt + ((dt * 16 + l15) * 72 + ks * 32 + quad * 8) * 2);
                ctx[it][dt] = __builtin_amdgcn_mfma_f32_16x16x32_bf16(pf, vf, ctx[it][dt], 0, 0, 0);
            }
        }
    }

    // ---- ctx/sum -> LDS (reuse Pb; same-wave order keeps it race-free) ----
#pragma unroll
    for (int it = 0; it < 4; ++it)
#pragma unroll
        for (int r = 0; r < 4; ++r) {
            const int i = it * 16 + quad * 4 + r;
            const u32 pk = cvt_pk_bf16(ctx[it][0][r] * inv[it][r], ctx[it][1][r] * inv[it][r]);
            *(short*)(Pb + (i * 36 + l15) * 2)      = (short)pk;
            *(short*)(Pb + (i * 36 + 16 + l15) * 2) = (short)(pk >> 16);
        }

    // ---- packed-A-layout store for proj GEMM ----
    const int tok = w * 64 + lane;
    const size_t obase = ((size_t)(tok >> 4) * 24 + h * 4) * 128 + (size_t)(tok & 15) * 8;
#pragma unroll
    for (int c = 0; c < 4; ++c) {
        const short8 row = *(const short8*)(Pb + (lane * 36 + c * 8) * 2);
        *(short8*)(Ctx + obase + (size_t)c * 128) = row;
    }
}

// ---------------- LN kernels ----------------

__global__ __launch_bounds__(256)
void ln_h(const bf16* __restrict__ X, const float* __restrict__ hidden,
          const float* __restrict__ g, const float* __restrict__ b,
          bf16* __restrict__ Hres, bf16* __restrict__ Hpk)
{
    const int lane = threadIdx.x & 63;
    const int wv = threadIdx.x >> 6;
    const int tok = blockIdx.x * 4 + wv;
    const int grow = gather_row(tok);
    __shared__ float rows[4][192];
    const bf16* xr = X + (size_t)tok * 192;
    const float x0 = bu2f(*(const unsigned short*)(xr + lane));
    const float x1 = bu2f(*(const unsigned short*)(xr + lane + 64));
    const float x2 = bu2f(*(const unsigned short*)(xr + lane + 128));
    float s = x0 + x1 + x2;
#pragma unroll
    for (int o = 32; o > 0; o >>= 1) s += __shfl_xor(s, o);
    const float mean = s * (1.0f / 192.0f);
    const float d0 = x0 - mean, d1 = x1 - mean, d2 = x2 - mean;
    float vsum = d0 * d0 + d1 * d1 + d2 * d2;
#pragma unroll
    for (int o = 32; o > 0; o >>= 1) vsum += __shfl_xor(vsum, o);
    const float rstd = rsqrtf(vsum * (1.0f / 192.0f) + 1e-5f);
    const float* hr = hidden + (size_t)grow * 192;
    const float h0 = hr[lane]       + d0 * rstd * g[lane]       + b[lane];
    const float h1 = hr[lane + 64]  + d1 * rstd * g[lane + 64]  + b[lane + 64];
    const float h2 = hr[lane + 128] + d2 * rstd * g[lane + 128] + b[lane + 128];
    bf16* hres = Hres + (size_t)tok * 192;
    *(unsigned short*)(hres + lane)       = f2bu(h0);
    *(unsigned short*)(hres + lane + 64)  = f2bu(h1);
    *(unsigned short*)(hres + lane + 128) = f2bu(h2);
    rows[wv][lane] = h0; rows[wv][lane + 64] = h1; rows[wv][lane + 128] = h2;
    __syncthreads();
    if (lane < 24) {
        short8 o;
#pragma unroll
        for (int j = 0; j < 8; ++j) o[j] = (short)f2bu(rows[wv][lane * 8 + j]);
        const int mtG = tok >> 4, mm = tok & 15;
        *(short8*)(Hpk + ((size_t)(mtG * 24 + lane) * 16 + mm) * 8) = o;
    }
}

__global__ __launch_bounds__(256)
void ln_out(const bf16* __restrict__ Y, const bf16* __restrict__ Hres,
            const float* __restrict__ g, const float* __restrict__ b,
            float* __restrict__ Out)
{
    const int lane = threadIdx.x & 63;
    const int tok = blockIdx.x * 4 + (threadIdx.x >> 6);
    const int grow = gather_row(tok);
    const bf16* yr = Y + (size_t)tok * 192;
    const float x0 = bu2f(*(const unsigned short*)(yr + lane));
    const float x1 = bu2f(*(const unsigned short*)(yr + lane + 64));
    const float x2 = bu2f(*(const unsigned short*)(yr + lane + 128));
    float s = x0 + x1 + x2;
#pragma unroll
    for (int o = 32; o > 0; o >>= 1) s += __shfl_xor(s, o);
    const float mean = s * (1.0f / 192.0f);
    const float d0 = x0 - mean, d1 = x1 - mean, d2 = x2 - mean;
    float vsum = d0 * d0 + d1 * d1 + d2 * d2;
#pragma unroll
    for (int o = 32; o > 0; o >>= 1) vsum += __shfl_xor(vsum, o);
    const float rstd = rsqrtf(vsum * (1.0f / 192.0f) + 1e-5f);
    const bf16* hr = Hres + (size_t)tok * 192;
    float* op = Out + (size_t)grow * 192;
    op[lane]       = bu2f(*(const unsigned short*)(hr + lane))       + d0 * rstd * g[lane]       + b[lane];
    op[lane + 64]  = bu2f(*(const unsigned short*)(hr + lane + 64))  + d1 * rstd * g[lane + 64]  + b[lane + 64];
    op[lane + 128] = bu2f(*(const unsigned short*)(hr + lane + 128)) + d2 * rstd * g[lane + 128] + b[lane + 128];
}

// ---------------- launch ----------------

extern "C" void kernel_launch(void* const* d_in, const int* in_sizes, int n_in,
                              void* d_out, int out_size, void* d_ws, size_t ws_size,
                              hipStream_t stream)
{
    const float* hidden = (const float*)d_in[0];
    const float* q_w = (const float*)d_in[1];
    const float* q_b = (const float*)d_in[2];
    const float* k_w = (const float*)d_in[3];
    const float* v_w = (const float*)d_in[4];
    const float* v_b = (const float*)d_in[5];
    const float* logit_scale = (const float*)d_in[6];
    const float* cpb_w1 = (const float*)d_in[7];
    const float* cpb_b1 = (const float*)d_in[8];
    const float* cpb_w2 = (const float*)d_in[9];
    const float* proj_w = (const float*)d_in[10];
    const float* proj_b = (const float*)d_in[11];
    const float* ln1_g = (const float*)d_in[12];
    const float* ln1_b = (const float*)d_in[13];
    const float* fc1_w = (const float*)d_in[14];
    const float* fc1_b = (const float*)d_in[15];
    const float* fc2_w = (const float*)d_in[16];
    const float* fc2_b = (const float*)d_in[17];
    const float* ln2_g = (const float*)d_in[18];
    const float* ln2_b = (const float*)d_in[19];

    char* ws = (char*)d_ws;
    bf16*  APK   = (bf16*)(ws + 0);
    float* RPB   = (float*)(ws + 0);
    bf16*  PROJW = (bf16*)(ws + (1 << 20));
    bf16*  MID   = (bf16*)(ws + 0);
    bf16*  CTX   = (bf16*)(ws + 56623104);
    bf16*  QKVW  = (bf16*)(ws + 56623104);
    float* QKVB  = (float*)(ws + 56844288);
    float* TAB   = (float*)(ws + 56846592);
    bf16*  QKV   = (bf16*)(ws + 113246208);
    bf16*  HRES  = (bf16*)(ws + 113246208);
    bf16*  HPK   = (bf16*)(ws + 169869312);
    bf16*  Y     = (bf16*)(ws + 226492416);
    bf16*  X     = (bf16*)(ws + 283115520);
    bf16*  FC1W  = (bf16*)(ws + 283115520);
    bf16*  FC2W  = (bf16*)(ws + 283262976);
    float* OUT   = (float*)d_out;

    cpb_mlp<<<225, 512, 0, stream>>>(cpb_w1, cpb_b1, cpb_w2, TAB);
    fuse_bias<<<3, 256, 0, stream>>>(q_b, v_b, QKVB);
    pack_w<<<18, 256, 0, stream>>>(q_w, QKVW,                 192, 192);
    pack_w<<<18, 256, 0, stream>>>(k_w, QKVW + 12 * 24 * 128, 192, 192);
    pack_w<<<18, 256, 0, stream>>>(v_w, QKVW + 24 * 24 * 128, 192, 192);
    conv_pack<<<13824, 256, 0, stream>>>(hidden, APK);

    gemm_mfma<192, false, EPI_NONE, 1, 3><<<1152, 256, 0, stream>>>(APK, QKVW, QKVB, QKV, 576);

    rpb_expand<<<96, 256, 0, stream>>>(TAB, logit_scale, RPB);
    pack_w<<<18, 256, 0, stream>>>(proj_w, PROJW, 192, 192);

    attn_mfma<<<3456, 256, 0, stream>>>(QKV, RPB, logit_scale, CTX);

    gemm_mfma<192, false, EPI_NONE, 1, 3><<<1152, 256, 0, stream>>>(CTX, PROJW, proj_b, X, 192);

    ln_h<<<NTOK / 4, 256, 0, stream>>>(X, hidden, ln1_g, ln1_b, HRES, HPK);

    pack_w<<<36, 256, 0, stream>>>(fc1_w, FC1W, 192, 384);
    pack_w<<<36, 256, 0, stream>>>(fc2_w, FC2W, 384, 192);

    gemm_mfma<192, true, EPI_GELU, 48, 3><<<1152, 256, 0, stream>>>(HPK, FC1W, fc1_b, MID, 384);
    gemm_mfma<384, false, EPI_NONE, 1, 2><<<1152, 256, 0, stream>>>(MID, FC2W, fc2_b, Y, 192);

    ln_out<<<NTOK / 4, 256, 0, stream>>>(Y, HRES, ln2_g, ln2_b, OUT);
}

// Round 5
// 621.631 us; speedup vs baseline: 1.2282x; 1.2282x over previous
//
#include <hip/hip_runtime.h>
#include <hip/hip_bf16.h>
#include <math.h>

typedef __hip_bfloat16 bf16;
typedef __attribute__((ext_vector_type(8))) short short8;
typedef __attribute__((ext_vector_type(4))) float floatx4;
typedef unsigned int u32;

#define NTOK 147456
#define IMG 384

__device__ __forceinline__ int gather_row(int m) {
    int gw = m >> 6, t = m & 63;
    int wr = gw / 48, wc = gw - wr * 48;
    int hh = wr * 8 + (t >> 3);
    int ww = wc * 8 + (t & 7);
    int oh = hh + 4; if (oh >= IMG) oh -= IMG;
    int ow = ww + 4; if (ow >= IMG) ow -= IMG;
    return oh * IMG + ow;
}

__device__ __forceinline__ unsigned short f2bu(float f) {
    unsigned u = __float_as_uint(f);
    unsigned r = (u + 0x7fffu + ((u >> 16) & 1u)) >> 16;   // RNE
    return (unsigned short)r;
}
__device__ __forceinline__ float bu2f(unsigned short u) {
    return __uint_as_float(((unsigned)u) << 16);
}

// HW packed f32->bf16 RNE conversion (same bits as f2bu)
__device__ __forceinline__ u32 cvt_pk_bf16(float lo, float hi) {
    u32 r;
    asm("v_cvt_pk_bf16_f32 %0, %1, %2" : "=v"(r) : "v"(lo), "v"(hi));
    return r;
}

// fast exact-GELU: 0.5*x*(1+erf(x/sqrt2)); erf via A&S 7.1.26, |err|<1.5e-7
__device__ __forceinline__ float gelu_fast(float x) {
    const float z = fabsf(x) * 0.70710678118654752f;
    const float t = __builtin_amdgcn_rcpf(fmaf(0.3275911f, z, 1.0f));
    float p = fmaf(1.061405429f, t, -1.453152027f);
    p = fmaf(p, t, 1.421413741f);
    p = fmaf(p, t, -0.284496736f);
    p = fmaf(p, t, 0.254829592f);
    p *= t;
    const float e = __expf(-z * z);
    float erfv = fmaf(-p, e, 1.0f);
    erfv = (x < 0.0f) ? -erfv : erfv;
    return 0.5f * x * (1.0f + erfv);
}

// ---------------- prep kernels ----------------

// hidden fp32 -> bf16 A-frag-packed, gathered window order: [mtG][kg24][m16][8]
__global__ __launch_bounds__(256)
void conv_pack(const float* __restrict__ hidden, bf16* __restrict__ Apk)
{
    const int cid = blockIdx.x * 256 + threadIdx.x;    // < 9216*24*16
    const int mtG = cid / 384;
    const int rest = cid - mtG * 384;
    const int kg = rest >> 4, mm = rest & 15;
    const int tok = mtG * 16 + mm;
    const float* p = hidden + (size_t)gather_row(tok) * 192 + kg * 8;
    const float4 a = *(const float4*)p;
    const float4 b = *(const float4*)(p + 4);
    short8 o;
    o[0] = (short)f2bu(a.x); o[1] = (short)f2bu(a.y);
    o[2] = (short)f2bu(a.z); o[3] = (short)f2bu(a.w);
    o[4] = (short)f2bu(b.x); o[5] = (short)f2bu(b.y);
    o[6] = (short)f2bu(b.z); o[7] = (short)f2bu(b.w);
    *(short8*)(Apk + (size_t)cid * 8) = o;
}

// W fp32 [K][N] row-major -> bf16 B-frag-packed [ntG][kg][n16][8]
__global__ __launch_bounds__(256)
void pack_w(const float* __restrict__ W, bf16* __restrict__ out, int K, int N)
{
    const int cid = blockIdx.x * 256 + threadIdx.x;
    const int KG = K >> 3;
    const int total = (N >> 4) * KG * 16;
    if (cid >= total) return;
    const int n = cid & 15;
    const int kg = (cid >> 4) % KG;
    const int ntG = (cid >> 4) / KG;
    short8 o;
#pragma unroll
    for (int j = 0; j < 8; ++j)
        o[j] = (short)f2bu(W[(size_t)(kg * 8 + j) * N + ntG * 16 + n]);
    *(short8*)(out + (size_t)cid * 8) = o;
}

__global__ __launch_bounds__(256)
void fuse_bias(const float* __restrict__ qb, const float* __restrict__ vb,
               float* __restrict__ out)
{
    const int t = blockIdx.x * 256 + threadIdx.x;
    if (t >= 576) return;
    out[t] = (t < 192) ? qb[t] : ((t < 384) ? 0.0f : vb[t - 384]);
}

// ---------------- MFMA GEMM (B-in-registers streaming) ----------------
#define EPI_NONE 0
#define EPI_GELU 1

// Memory-bound regime: per-GEMM FLOPs need only ~13us of MFMA pipe but
// A+C traffic is 110-220 MB (~20-35us at HBM). Design: each wave owns one
// N-slab (NT*16 cols) and a strip of SMT 16-row M-tiles. Its B-frags live
// in VGPRs for the whole strip (loaded once, L1/L2-hot); the main loop is
// a pure HBM stream: KT coalesced A-loads -> KT*NT MFMAs -> store. No
// barriers, no main-loop LDS (epilogue transpose is wave-private), no
// redundant B reads. Waves of a block take consecutive strips of the same
// slab (shared B in L1, contiguous A in L2).
template<int KDIM, int NT, int SMT, bool PACK_OUT, int EPI, int KGOUT, int MW>
__global__ __launch_bounds__(256, MW)
void gemm_rs(const bf16* __restrict__ Apk, const bf16* __restrict__ Bpk,
             const float* __restrict__ bias, bf16* __restrict__ C, int N)
{
    constexpr int KG = KDIM / 8;          // k-groups of 8
    constexpr int KT = KDIM / 32;         // 32-wide k tiles
    constexpr int NSTRIP = (NTOK / 16) / SMT;
    constexpr int PITCH = NT * 16 + 8;    // LDS transpose pitch (shorts)
    __shared__ __align__(16) char wbs[4][16 * PITCH * 2];
    const int wave = threadIdx.x >> 6, lane = threadIdx.x & 63;
    const int l15 = lane & 15, quad = lane >> 4;
    const int wid = blockIdx.x * 4 + wave;
    const int ns = wid / NSTRIP;          // N-slab
    const int si = wid % NSTRIP;          // M-strip
    char* wb = wbs[wave];
    const char* Asrc = (const char*)Apk;
    const char* Bsrc = (const char*)Bpk;

    // ---- B slab -> registers, once per wave ----
    short8 breg[NT][KT];
#pragma unroll
    for (int nt = 0; nt < NT; ++nt)
#pragma unroll
        for (int kt = 0; kt < KT; ++kt)
            breg[nt][kt] = *(const short8*)(Bsrc +
                (size_t)((ns * NT + nt) * KG + kt * 4) * 256 + lane * 16);

    float bv[NT];
#pragma unroll
    for (int nt = 0; nt < NT; ++nt)
        bv[nt] = bias ? bias[ns * (NT * 16) + nt * 16 + l15] : 0.0f;

    for (int t = 0; t < SMT; ++t) {
        const int mt = si * SMT + t;
        // ---- A tile (16 rows x KDIM): KT independent coalesced 1 KiB loads ----
        short8 a[KT];
#pragma unroll
        for (int kt = 0; kt < KT; ++kt)
            a[kt] = *(const short8*)(Asrc + (size_t)(mt * KG + kt * 4) * 256 + lane * 16);

        floatx4 acc[NT];
#pragma unroll
        for (int nt = 0; nt < NT; ++nt)
            acc[nt] = (floatx4){0.f, 0.f, 0.f, 0.f};
#pragma unroll
        for (int kt = 0; kt < KT; ++kt)
#pragma unroll
            for (int nt = 0; nt < NT; ++nt)
                acc[nt] = __builtin_amdgcn_mfma_f32_16x16x32_bf16(a[kt], breg[nt][kt], acc[nt], 0, 0, 0);

        // ---- epilogue: bias (+gelu), bf16, wave-private LDS transpose ----
#pragma unroll
        for (int nt = 0; nt < NT; ++nt) {
            const int c = nt * 16 + l15;
#pragma unroll
            for (int i = 0; i < 4; ++i) {
                float f = acc[nt][i] + bv[nt];
                if (EPI == EPI_GELU)
                    f = gelu_fast(f);
                const int r = quad * 4 + i;
                *(unsigned short*)(wb + (r * PITCH + c) * 2) = f2bu(f);
            }
        }
        if (PACK_OUT) {           // NT==4: packed [mt][kg][16][8] for next GEMM
#pragma unroll
            for (int i = 0; i < 2; ++i) {
                const int cg = i * 4 + quad;                       // 0..7
                const short8 row = *(const short8*)(wb + (l15 * PITCH + cg * 8) * 2);
                bf16* dst = C + ((size_t)(mt * KGOUT + ns * 8 + cg) * 16 + l15) * 8;
                *(short8*)dst = row;
            }
        } else if (NT == 4) {     // full-128B-line stores
            const int mr = lane >> 3, c2 = (lane & 7) * 8;
#pragma unroll
            for (int i = 0; i < 2; ++i) {
                const int rr = i * 8 + mr;
                const short8 row = *(const short8*)(wb + (rr * PITCH + c2) * 2);
                *(short8*)(C + (size_t)(mt * 16 + rr) * N + ns * 64 + c2) = row;
            }
        } else {                  // NT==2: one 16B store per lane
            const int mr = lane >> 2, c2 = (lane & 3) * 8;
            const short8 row = *(const short8*)(wb + (mr * PITCH + c2) * 2);
            *(short8*)(C + (size_t)(mt * 16 + mr) * N + ns * 32 + c2) = row;
        }
    }
}

// ---------------- CPB MLP + RPB ----------------

__device__ __forceinline__ float cpb_coord(int i) {
    float a = (float)(i - 7) * (8.0f / 7.0f);
    float s = (a > 0.f) ? 1.f : ((a < 0.f) ? -1.f : 0.f);
    return s * log2f(fabsf(a) + 1.0f) * (1.0f / 3.0f);
}

__global__ __launch_bounds__(512)
void cpb_mlp(const float* __restrict__ w1, const float* __restrict__ b1,
             const float* __restrict__ w2, float* __restrict__ tab)
{
    const int r = blockIdx.x;
    const int t = threadIdx.x;
    const float x0 = cpb_coord(r / 15);
    const float x1 = cpb_coord(r % 15);
    const float hgt = fmaxf(x0 * w1[t] + x1 * w1[512 + t] + b1[t], 0.0f);
    __shared__ float red[512];
    for (int n = 0; n < 6; ++n) {
        red[t] = hgt * w2[t * 6 + n];
        __syncthreads();
        for (int s = 256; s > 0; s >>= 1) {
            if (t < s) red[t] += red[t + s];
            __syncthreads();
        }
        if (t == 0) tab[r * 6 + n] = red[0];
        __syncthreads();
    }
}

// rpb' = 16*sigmoid(v) - (scale_h + 16): folds the softmax constant-shift C
// so attn can do exp(S*scale + rpb') directly (no row-max pass).
__global__ __launch_bounds__(256)
void rpb_expand(const float* __restrict__ tab, const float* __restrict__ logit_scale,
                float* __restrict__ rpb)
{
    const int idx = blockIdx.x * 256 + threadIdx.x;
    if (idx >= 6 * 4096) return;
    const int h = idx >> 12;
    const int t = (idx >> 6) & 63;
    const int j = idx & 63;
    const int pr = t >> 3, pc = t & 7, qr = j >> 3, qc = j & 7;
    const int ridx = (pr - qr + 7) * 15 + (pc - qc + 7);
    const float v = tab[ridx * 6 + h];
    const float scale = __expf(fminf(logit_scale[h], 4.6051701859880914f));
    rpb[idx] = 16.0f / (1.0f + expf(-v)) - scale - 16.0f;
}

// ---------------- MFMA attention ----------------
// one wave per (window, head); 4 waves/block; all LDS wave-private (no barriers).
// Raw bf16 Q/K frags feed QK^T directly; cosine norms applied to the f32
// accumulator (rnk lane-local, rnq via 16 shfls). Softmax uses a constant
// shift C=scale+16 (pre-folded into rpb) instead of a row-max pass.
__global__ __launch_bounds__(256, 2)
void attn_mfma(const bf16* __restrict__ QKV, const float* __restrict__ rpb,
               const float* __restrict__ logit_scale, bf16* __restrict__ Ctx)
{
    __shared__ __align__(16) char lds[4][9216];
    const int wave = threadIdx.x >> 6, lane = threadIdx.x & 63;
    const int l15 = lane & 15, quad = lane >> 4;
    const int wh = blockIdx.x * 4 + wave;
    const int w = wh / 6, h = wh - w * 6;
    char* Pb = lds[wave];            // 64 rows x 36 bf16 (P halves, then ctx)
    char* Vt = lds[wave] + 4608;     // 32 rows x 72 bf16 (V transposed)

    const bf16* wbase = QKV + (size_t)w * 64 * 576;

    // ---- stage V^T: lane = token, writes its column (2 lanes/bank: free) ----
    {
        const bf16* vp = wbase + (size_t)lane * 576 + 384 + h * 32;
        const short8 v0 = *(const short8*)(vp);
        const short8 v1 = *(const short8*)(vp + 8);
        const short8 v2 = *(const short8*)(vp + 16);
        const short8 v3 = *(const short8*)(vp + 24);
#pragma unroll
        for (int j = 0; j < 8; ++j) {
            *(short*)(Vt + ((j     ) * 72 + lane) * 2) = v0[j];
            *(short*)(Vt + ((j +  8) * 72 + lane) * 2) = v1[j];
            *(short*)(Vt + ((j + 16) * 72 + lane) * 2) = v2[j];
            *(short*)(Vt + ((j + 24) * 72 + lane) * 2) = v3[j];
        }
    }

    // ---- region ids (mask only matters on last window row/col) ----
    const int wr = w / 48, wc = w - wr * 48;
    const bool edge = (wr == 47) || (wc == 47);
    int rid_j[4];
    if (edge) {
#pragma unroll
        for (int jt = 0; jt < 4; ++jt) {
            const int t = jt * 16 + l15;
            const int rr = (wr == 47) ? (((t >> 3) < 4) ? 1 : 2) : 0;
            const int rc = (wc == 47) ? (((t & 7) < 4) ? 1 : 2) : 0;
            rid_j[jt] = rr * 3 + rc;
        }
    }

    const float scale = __expf(fminf(logit_scale[h], 4.6051701859880914f));

    // ---- K frags (raw bf16) + per-col inverse norms ----
    short8 kfr[4];
    float rnk[4];
#pragma unroll
    for (int jt = 0; jt < 4; ++jt) {
        kfr[jt] = *(const short8*)(wbase + (size_t)(jt * 16 + l15) * 576 + 192 + h * 32 + quad * 8);
        float ss = 0.f;
#pragma unroll
        for (int j = 0; j < 8; ++j) {
            const float f = bu2f((unsigned short)kfr[jt][j]);
            ss = fmaf(f, f, ss);
        }
        ss += __shfl_xor(ss, 16); ss += __shfl_xor(ss, 32);
        rnk[jt] = __builtin_amdgcn_rcpf(fmaxf(__builtin_amdgcn_sqrtf(ss), 1e-12f));
    }

    // ---- S = Q K^T on raw frags; per-row inverse norms (scale folded) ----
    floatx4 acc[4][4];
    float rnq[4];
#pragma unroll
    for (int it = 0; it < 4; ++it)
#pragma unroll
        for (int jt = 0; jt < 4; ++jt)
            acc[it][jt] = (floatx4){0.f, 0.f, 0.f, 0.f};
#pragma unroll
    for (int it = 0; it < 4; ++it) {
        const short8 qf = *(const short8*)(wbase + (size_t)(it * 16 + l15) * 576 + h * 32 + quad * 8);
        float ss = 0.f;
#pragma unroll
        for (int j = 0; j < 8; ++j) {
            const float f = bu2f((unsigned short)qf[j]);
            ss = fmaf(f, f, ss);
        }
        ss += __shfl_xor(ss, 16); ss += __shfl_xor(ss, 32);
        rnq[it] = scale * __builtin_amdgcn_rcpf(fmaxf(__builtin_amdgcn_sqrtf(ss), 1e-12f));
#pragma unroll
        for (int jt = 0; jt < 4; ++jt)
            acc[it][jt] = __builtin_amdgcn_mfma_f32_16x16x32_bf16(qf, kfr[jt], acc[it][jt], 0, 0, 0);
    }

    const float* rpbh = rpb + h * 4096;   // already has -(scale+16) folded in

    // ---- normalize + bias + mask + exp + row-sum (no max pass) ----
    float inv[4][4];
#pragma unroll
    for (int it = 0; it < 4; ++it) {
#pragma unroll
        for (int r = 0; r < 4; ++r) {
            const int i = it * 16 + quad * 4 + r;
            const float rq = __shfl(rnq[it], quad * 4 + r);
            int rid_i = 0;
            if (edge) {
                const int rr = (wr == 47) ? (((i >> 3) < 4) ? 1 : 2) : 0;
                const int rc = (wc == 47) ? (((i & 7) < 4) ? 1 : 2) : 0;
                rid_i = rr * 3 + rc;
            }
            float s = 0.f;
#pragma unroll
            for (int jt = 0; jt < 4; ++jt) {
                float v = fmaf(acc[it][jt][r], rq * rnk[jt], rpbh[i * 64 + jt * 16 + l15]);
                if (edge && rid_i != rid_j[jt]) v -= 200.0f;   // mask added twice in ref
                const float e = __expf(v);
                acc[it][jt][r] = e; s += e;
            }
            s += __shfl_xor(s, 1); s += __shfl_xor(s, 2);
            s += __shfl_xor(s, 4); s += __shfl_xor(s, 8);
            inv[it][r] = __builtin_amdgcn_rcpf(s);
        }
    }

    // ---- ctx = P V via LDS round-trip in two 32-key halves ----
    floatx4 ctx[4][2];
#pragma unroll
    for (int it = 0; it < 4; ++it)
#pragma unroll
        for (int dt = 0; dt < 2; ++dt)
            ctx[it][dt] = (floatx4){0.f, 0.f, 0.f, 0.f};

#pragma unroll
    for (int ks = 0; ks < 2; ++ks) {
#pragma unroll
        for (int it = 0; it < 4; ++it)
#pragma unroll
            for (int r = 0; r < 4; ++r) {
                const int i = it * 16 + quad * 4 + r;
                const u32 pk = cvt_pk_bf16(acc[it][ks * 2][r], acc[it][ks * 2 + 1][r]);
                *(short*)(Pb + (i * 36 + l15) * 2)      = (short)pk;
                *(short*)(Pb + (i * 36 + 16 + l15) * 2) = (short)(pk >> 16);
            }
#pragma unroll
        for (int it = 0; it < 4; ++it) {
            const short8 pf = *(const short8*)(Pb + ((it * 16 + l15) * 36 + quad * 8) * 2);
#pragma unroll
            for (int dt = 0; dt < 2; ++dt) {
                const short8 vf = *(const short8*)(Vt + ((dt * 16 + l15) * 72 + ks * 32 + quad * 8) * 2);
                ctx[it][dt] = __builtin_amdgcn_mfma_f32_16x16x32_bf16(pf, vf, ctx[it][dt], 0, 0, 0);
            }
        }
    }

    // ---- ctx/sum -> LDS (reuse Pb; same-wave order keeps it race-free) ----
#pragma unroll
    for (int it = 0; it < 4; ++it)
#pragma unroll
        for (int r = 0; r < 4; ++r) {
            const int i = it * 16 + quad * 4 + r;
            const u32 pk = cvt_pk_bf16(ctx[it][0][r] * inv[it][r], ctx[it][1][r] * inv[it][r]);
            *(short*)(Pb + (i * 36 + l15) * 2)      = (short)pk;
            *(short*)(Pb + (i * 36 + 16 + l15) * 2) = (short)(pk >> 16);
        }

    // ---- packed-A-layout store for proj GEMM ----
    const int tok = w * 64 + lane;
    const size_t obase = ((size_t)(tok >> 4) * 24 + h * 4) * 128 + (size_t)(tok & 15) * 8;
#pragma unroll
    for (int c = 0; c < 4; ++c) {
        const short8 row = *(const short8*)(Pb + (lane * 36 + c * 8) * 2);
        *(short8*)(Ctx + obase + (size_t)c * 128) = row;
    }
}

// ---------------- LN kernels ----------------

__global__ __launch_bounds__(256)
void ln_h(const bf16* __restrict__ X, const float* __restrict__ hidden,
          const float* __restrict__ g, const float* __restrict__ b,
          bf16* __restrict__ Hres, bf16* __restrict__ Hpk)
{
    const int lane = threadIdx.x & 63;
    const int wv = threadIdx.x >> 6;
    const int tok = blockIdx.x * 4 + wv;
    const int grow = gather_row(tok);
    __shared__ float rows[4][192];
    const bf16* xr = X + (size_t)tok * 192;
    const float x0 = bu2f(*(const unsigned short*)(xr + lane));
    const float x1 = bu2f(*(const unsigned short*)(xr + lane + 64));
    const float x2 = bu2f(*(const unsigned short*)(xr + lane + 128));
    float s = x0 + x1 + x2;
#pragma unroll
    for (int o = 32; o > 0; o >>= 1) s += __shfl_xor(s, o);
    const float mean = s * (1.0f / 192.0f);
    const float d0 = x0 - mean, d1 = x1 - mean, d2 = x2 - mean;
    float vsum = d0 * d0 + d1 * d1 + d2 * d2;
#pragma unroll
    for (int o = 32; o > 0; o >>= 1) vsum += __shfl_xor(vsum, o);
    const float rstd = rsqrtf(vsum * (1.0f / 192.0f) + 1e-5f);
    const float* hr = hidden + (size_t)grow * 192;
    const float h0 = hr[lane]       + d0 * rstd * g[lane]       + b[lane];
    const float h1 = hr[lane + 64]  + d1 * rstd * g[lane + 64]  + b[lane + 64];
    const float h2 = hr[lane + 128] + d2 * rstd * g[lane + 128] + b[lane + 128];
    bf16* hres = Hres + (size_t)tok * 192;
    *(unsigned short*)(hres + lane)       = f2bu(h0);
    *(unsigned short*)(hres + lane + 64)  = f2bu(h1);
    *(unsigned short*)(hres + lane + 128) = f2bu(h2);
    rows[wv][lane] = h0; rows[wv][lane + 64] = h1; rows[wv][lane + 128] = h2;
    __syncthreads();
    if (lane < 24) {
        short8 o;
#pragma unroll
        for (int j = 0; j < 8; ++j) o[j] = (short)f2bu(rows[wv][lane * 8 + j]);
        const int mtG = tok >> 4, mm = tok & 15;
        *(short8*)(Hpk + ((size_t)(mtG * 24 + lane) * 16 + mm) * 8) = o;
    }
}

__global__ __launch_bounds__(256)
void ln_out(const bf16* __restrict__ Y, const bf16* __restrict__ Hres,
            const float* __restrict__ g, const float* __restrict__ b,
            float* __restrict__ Out)
{
    const int lane = threadIdx.x & 63;
    const int tok = blockIdx.x * 4 + (threadIdx.x >> 6);
    const int grow = gather_row(tok);
    const bf16* yr = Y + (size_t)tok * 192;
    const float x0 = bu2f(*(const unsigned short*)(yr + lane));
    const float x1 = bu2f(*(const unsigned short*)(yr + lane + 64));
    const float x2 = bu2f(*(const unsigned short*)(yr + lane + 128));
    float s = x0 + x1 + x2;
#pragma unroll
    for (int o = 32; o > 0; o >>= 1) s += __shfl_xor(s, o);
    const float mean = s * (1.0f / 192.0f);
    const float d0 = x0 - mean, d1 = x1 - mean, d2 = x2 - mean;
    float vsum = d0 * d0 + d1 * d1 + d2 * d2;
#pragma unroll
    for (int o = 32; o > 0; o >>= 1) vsum += __shfl_xor(vsum, o);
    const float rstd = rsqrtf(vsum * (1.0f / 192.0f) + 1e-5f);
    const bf16* hr = Hres + (size_t)tok * 192;
    float* op = Out + (size_t)grow * 192;
    op[lane]       = bu2f(*(const unsigned short*)(hr + lane))       + d0 * rstd * g[lane]       + b[lane];
    op[lane + 64]  = bu2f(*(const unsigned short*)(hr + lane + 64))  + d1 * rstd * g[lane + 64]  + b[lane + 64];
    op[lane + 128] = bu2f(*(const unsigned short*)(hr + lane + 128)) + d2 * rstd * g[lane + 128] + b[lane + 128];
}

// ---------------- launch ----------------

extern "C" void kernel_launch(void* const* d_in, const int* in_sizes, int n_in,
                              void* d_out, int out_size, void* d_ws, size_t ws_size,
                              hipStream_t stream)
{
    const float* hidden = (const float*)d_in[0];
    const float* q_w = (const float*)d_in[1];
    const float* q_b = (const float*)d_in[2];
    const float* k_w = (const float*)d_in[3];
    const float* v_w = (const float*)d_in[4];
    const float* v_b = (const float*)d_in[5];
    const float* logit_scale = (const float*)d_in[6];
    const float* cpb_w1 = (const float*)d_in[7];
    const float* cpb_b1 = (const float*)d_in[8];
    const float* cpb_w2 = (const float*)d_in[9];
    const float* proj_w = (const float*)d_in[10];
    const float* proj_b = (const float*)d_in[11];
    const float* ln1_g = (const float*)d_in[12];
    const float* ln1_b = (const float*)d_in[13];
    const float* fc1_w = (const float*)d_in[14];
    const float* fc1_b = (const float*)d_in[15];
    const float* fc2_w = (const float*)d_in[16];
    const float* fc2_b = (const float*)d_in[17];
    const float* ln2_g = (const float*)d_in[18];
    const float* ln2_b = (const float*)d_in[19];

    char* ws = (char*)d_ws;
    bf16*  APK   = (bf16*)(ws + 0);
    float* RPB   = (float*)(ws + 0);
    bf16*  PROJW = (bf16*)(ws + (1 << 20));
    bf16*  MID   = (bf16*)(ws + 0);
    bf16*  CTX   = (bf16*)(ws + 56623104);
    bf16*  QKVW  = (bf16*)(ws + 56623104);
    float* QKVB  = (float*)(ws + 56844288);
    float* TAB   = (float*)(ws + 56846592);
    bf16*  QKV   = (bf16*)(ws + 113246208);
    bf16*  HRES  = (bf16*)(ws + 113246208);
    bf16*  HPK   = (bf16*)(ws + 169869312);
    bf16*  Y     = (bf16*)(ws + 226492416);
    bf16*  X     = (bf16*)(ws + 283115520);
    bf16*  FC1W  = (bf16*)(ws + 283115520);
    bf16*  FC2W  = (bf16*)(ws + 283262976);
    float* OUT   = (float*)d_out;

    cpb_mlp<<<225, 512, 0, stream>>>(cpb_w1, cpb_b1, cpb_w2, TAB);
    fuse_bias<<<3, 256, 0, stream>>>(q_b, v_b, QKVB);
    pack_w<<<18, 256, 0, stream>>>(q_w, QKVW,                 192, 192);
    pack_w<<<18, 256, 0, stream>>>(k_w, QKVW + 12 * 24 * 128, 192, 192);
    pack_w<<<18, 256, 0, stream>>>(v_w, QKVW + 24 * 24 * 128, 192, 192);
    conv_pack<<<13824, 256, 0, stream>>>(hidden, APK);

    // QKV: K=192, N=576 (9 slabs), strip=288 rows -> 9*512/4 = 1152 blocks
    gemm_rs<192, 4, 18, false, EPI_NONE, 1, 3><<<1152, 256, 0, stream>>>(APK, QKVW, QKVB, QKV, 576);

    rpb_expand<<<96, 256, 0, stream>>>(TAB, logit_scale, RPB);
    pack_w<<<18, 256, 0, stream>>>(proj_w, PROJW, 192, 192);

    attn_mfma<<<3456, 256, 0, stream>>>(QKV, RPB, logit_scale, CTX);

    // proj: K=192, N=192 (3 slabs), strip=144 rows -> 3*1024/4 = 768 blocks
    gemm_rs<192, 4, 9, false, EPI_NONE, 1, 3><<<768, 256, 0, stream>>>(CTX, PROJW, proj_b, X, 192);

    ln_h<<<NTOK / 4, 256, 0, stream>>>(X, hidden, ln1_g, ln1_b, HRES, HPK);

    pack_w<<<36, 256, 0, stream>>>(fc1_w, FC1W, 192, 384);
    pack_w<<<36, 256, 0, stream>>>(fc2_w, FC2W, 384, 192);

    // fc1: K=192, N=384 (6 slabs), packed out (KGOUT=48) -> 6*512/4 = 768 blocks
    gemm_rs<192, 4, 18, true, EPI_GELU, 48, 3><<<768, 256, 0, stream>>>(HPK, FC1W, fc1_b, MID, 384);
    // fc2: K=384, N=192, NT=2 (6 slabs of 32) -> 6*512/4 = 768 blocks
    gemm_rs<384, 2, 18, false, EPI_NONE, 1, 2><<<768, 256, 0, stream>>>(MID, FC2W, fc2_b, Y, 192);

    ln_out<<<NTOK / 4, 256, 0, stream>>>(Y, HRES, ln2_g, ln2_b, OUT);
}

// Round 6
// 604.586 us; speedup vs baseline: 1.2628x; 1.0282x over previous
//
#include <hip/hip_runtime.h>
#include <hip/hip_bf16.h>
#include <math.h>

typedef __hip_bfloat16 bf16;
typedef __attribute__((ext_vector_type(8))) short short8;
typedef __attribute__((ext_vector_type(4))) float floatx4;
typedef unsigned int u32;

#define NTOK 147456
#define IMG 384

__device__ __forceinline__ int gather_row(int m) {
    int gw = m >> 6, t = m & 63;
    int wr = gw / 48, wc = gw - wr * 48;
    int hh = wr * 8 + (t >> 3);
    int ww = wc * 8 + (t & 7);
    int oh = hh + 4; if (oh >= IMG) oh -= IMG;
    int ow = ww + 4; if (ow >= IMG) ow -= IMG;
    return oh * IMG + ow;
}

__device__ __forceinline__ unsigned short f2bu(float f) {
    unsigned u = __float_as_uint(f);
    unsigned r = (u + 0x7fffu + ((u >> 16) & 1u)) >> 16;   // RNE
    return (unsigned short)r;
}
__device__ __forceinline__ float bu2f(unsigned short u) {
    return __uint_as_float(((unsigned)u) << 16);
}

// HW packed f32->bf16 RNE conversion (same bits as f2bu)
__device__ __forceinline__ u32 cvt_pk_bf16(float lo, float hi) {
    u32 r;
    asm("v_cvt_pk_bf16_f32 %0, %1, %2" : "=v"(r) : "v"(lo), "v"(hi));
    return r;
}

// fast exact-GELU: 0.5*x*(1+erf(x/sqrt2)); erf via A&S 7.1.26, |err|<1.5e-7
__device__ __forceinline__ float gelu_fast(float x) {
    const float z = fabsf(x) * 0.70710678118654752f;
    const float t = __builtin_amdgcn_rcpf(fmaf(0.3275911f, z, 1.0f));
    float p = fmaf(1.061405429f, t, -1.453152027f);
    p = fmaf(p, t, 1.421413741f);
    p = fmaf(p, t, -0.284496736f);
    p = fmaf(p, t, 0.254829592f);
    p *= t;
    const float e = __expf(-z * z);
    float erfv = fmaf(-p, e, 1.0f);
    erfv = (x < 0.0f) ? -erfv : erfv;
    return 0.5f * x * (1.0f + erfv);
}

// ---------------- prep kernels ----------------

// hidden fp32 -> bf16 A-frag-packed, gathered window order: [mtG][kg24][m16][8]
__global__ __launch_bounds__(256)
void conv_pack(const float* __restrict__ hidden, bf16* __restrict__ Apk)
{
    const int cid = blockIdx.x * 256 + threadIdx.x;    // < 9216*24*16
    const int mtG = cid / 384;
    const int rest = cid - mtG * 384;
    const int kg = rest >> 4, mm = rest & 15;
    const int tok = mtG * 16 + mm;
    const float* p = hidden + (size_t)gather_row(tok) * 192 + kg * 8;
    const float4 a = *(const float4*)p;
    const float4 b = *(const float4*)(p + 4);
    short8 o;
    o[0] = (short)f2bu(a.x); o[1] = (short)f2bu(a.y);
    o[2] = (short)f2bu(a.z); o[3] = (short)f2bu(a.w);
    o[4] = (short)f2bu(b.x); o[5] = (short)f2bu(b.y);
    o[6] = (short)f2bu(b.z); o[7] = (short)f2bu(b.w);
    *(short8*)(Apk + (size_t)cid * 8) = o;
}

// W fp32 [K][N] row-major -> bf16 B-frag-packed [ntG][kg][n16][8]
__global__ __launch_bounds__(256)
void pack_w(const float* __restrict__ W, bf16* __restrict__ out, int K, int N)
{
    const int cid = blockIdx.x * 256 + threadIdx.x;
    const int KG = K >> 3;
    const int total = (N >> 4) * KG * 16;
    if (cid >= total) return;
    const int n = cid & 15;
    const int kg = (cid >> 4) % KG;
    const int ntG = (cid >> 4) / KG;
    short8 o;
#pragma unroll
    for (int j = 0; j < 8; ++j)
        o[j] = (short)f2bu(W[(size_t)(kg * 8 + j) * N + ntG * 16 + n]);
    *(short8*)(out + (size_t)cid * 8) = o;
}

__global__ __launch_bounds__(256)
void fuse_bias(const float* __restrict__ qb, const float* __restrict__ vb,
               float* __restrict__ out)
{
    const int t = blockIdx.x * 256 + threadIdx.x;
    if (t >= 576) return;
    out[t] = (t < 192) ? qb[t] : ((t < 384) ? 0.0f : vb[t - 384]);
}

// ---------------- MFMA GEMM (B-in-registers streaming) ----------------
#define EPI_NONE 0
#define EPI_GELU 1

// Memory-bound regime: each wave owns one N-slab (NT*16 cols) and a strip
// of SMT 16-row M-tiles. B-frags live in VGPRs for the whole strip; the
// main loop is a pure HBM stream: KT coalesced A-loads -> KT*NT MFMAs ->
// store. No barriers, no main-loop LDS, no redundant B reads.
template<int KDIM, int NT, int SMT, bool PACK_OUT, int EPI, int KGOUT, int MW>
__global__ __launch_bounds__(256, MW)
void gemm_rs(const bf16* __restrict__ Apk, const bf16* __restrict__ Bpk,
             const float* __restrict__ bias, bf16* __restrict__ C, int N)
{
    constexpr int KG = KDIM / 8;          // k-groups of 8
    constexpr int KT = KDIM / 32;         // 32-wide k tiles
    constexpr int NSTRIP = (NTOK / 16) / SMT;
    constexpr int PITCH = NT * 16 + 8;    // LDS transpose pitch (shorts)
    __shared__ __align__(16) char wbs[4][16 * PITCH * 2];
    const int wave = threadIdx.x >> 6, lane = threadIdx.x & 63;
    const int l15 = lane & 15, quad = lane >> 4;
    const int wid = blockIdx.x * 4 + wave;
    const int ns = wid / NSTRIP;          // N-slab
    const int si = wid % NSTRIP;          // M-strip
    char* wb = wbs[wave];
    const char* Asrc = (const char*)Apk;
    const char* Bsrc = (const char*)Bpk;

    // ---- B slab -> registers, once per wave ----
    short8 breg[NT][KT];
#pragma unroll
    for (int nt = 0; nt < NT; ++nt)
#pragma unroll
        for (int kt = 0; kt < KT; ++kt)
            breg[nt][kt] = *(const short8*)(Bsrc +
                (size_t)((ns * NT + nt) * KG + kt * 4) * 256 + lane * 16);

    float bv[NT];
#pragma unroll
    for (int nt = 0; nt < NT; ++nt)
        bv[nt] = bias ? bias[ns * (NT * 16) + nt * 16 + l15] : 0.0f;

    for (int t = 0; t < SMT; ++t) {
        const int mt = si * SMT + t;
        // ---- A tile (16 rows x KDIM): KT independent coalesced 1 KiB loads ----
        short8 a[KT];
#pragma unroll
        for (int kt = 0; kt < KT; ++kt)
            a[kt] = *(const short8*)(Asrc + (size_t)(mt * KG + kt * 4) * 256 + lane * 16);

        floatx4 acc[NT];
#pragma unroll
        for (int nt = 0; nt < NT; ++nt)
            acc[nt] = (floatx4){0.f, 0.f, 0.f, 0.f};
#pragma unroll
        for (int kt = 0; kt < KT; ++kt)
#pragma unroll
            for (int nt = 0; nt < NT; ++nt)
                acc[nt] = __builtin_amdgcn_mfma_f32_16x16x32_bf16(a[kt], breg[nt][kt], acc[nt], 0, 0, 0);

        // ---- epilogue: bias (+gelu), bf16, wave-private LDS transpose ----
#pragma unroll
        for (int nt = 0; nt < NT; ++nt) {
            const int c = nt * 16 + l15;
#pragma unroll
            for (int i = 0; i < 4; ++i) {
                float f = acc[nt][i] + bv[nt];
                if (EPI == EPI_GELU)
                    f = gelu_fast(f);
                const int r = quad * 4 + i;
                *(unsigned short*)(wb + (r * PITCH + c) * 2) = f2bu(f);
            }
        }
        if (PACK_OUT) {           // NT==4: packed [mt][kg][16][8] for next GEMM
#pragma unroll
            for (int i = 0; i < 2; ++i) {
                const int cg = i * 4 + quad;                       // 0..7
                const short8 row = *(const short8*)(wb + (l15 * PITCH + cg * 8) * 2);
                bf16* dst = C + ((size_t)(mt * KGOUT + ns * 8 + cg) * 16 + l15) * 8;
                *(short8*)dst = row;
            }
        } else if (NT == 4) {     // full-128B-line stores
            const int mr = lane >> 3, c2 = (lane & 7) * 8;
#pragma unroll
            for (int i = 0; i < 2; ++i) {
                const int rr = i * 8 + mr;
                const short8 row = *(const short8*)(wb + (rr * PITCH + c2) * 2);
                *(short8*)(C + (size_t)(mt * 16 + rr) * N + ns * 64 + c2) = row;
            }
        } else {                  // NT==2: one 16B store per lane
            const int mr = lane >> 2, c2 = (lane & 3) * 8;
            const short8 row = *(const short8*)(wb + (mr * PITCH + c2) * 2);
            *(short8*)(C + (size_t)(mt * 16 + mr) * N + ns * 32 + c2) = row;
        }
    }
}

// ---------------- CPB MLP + RPB ----------------

__device__ __forceinline__ float cpb_coord(int i) {
    float a = (float)(i - 7) * (8.0f / 7.0f);
    float s = (a > 0.f) ? 1.f : ((a < 0.f) ? -1.f : 0.f);
    return s * log2f(fabsf(a) + 1.0f) * (1.0f / 3.0f);
}

__global__ __launch_bounds__(512)
void cpb_mlp(const float* __restrict__ w1, const float* __restrict__ b1,
             const float* __restrict__ w2, float* __restrict__ tab)
{
    const int r = blockIdx.x;
    const int t = threadIdx.x;
    const float x0 = cpb_coord(r / 15);
    const float x1 = cpb_coord(r % 15);
    const float hgt = fmaxf(x0 * w1[t] + x1 * w1[512 + t] + b1[t], 0.0f);
    __shared__ float red[512];
    for (int n = 0; n < 6; ++n) {
        red[t] = hgt * w2[t * 6 + n];
        __syncthreads();
        for (int s = 256; s > 0; s >>= 1) {
            if (t < s) red[t] += red[t + s];
            __syncthreads();
        }
        if (t == 0) tab[r * 6 + n] = red[0];
        __syncthreads();
    }
}

// rpb' = 16*sigmoid(v) - (scale_h + 16): folds the softmax constant-shift C
// so attn can do exp(S*scale + rpb') directly (no row-max pass).
__global__ __launch_bounds__(256)
void rpb_expand(const float* __restrict__ tab, const float* __restrict__ logit_scale,
                float* __restrict__ rpb)
{
    const int idx = blockIdx.x * 256 + threadIdx.x;
    if (idx >= 6 * 4096) return;
    const int h = idx >> 12;
    const int t = (idx >> 6) & 63;
    const int j = idx & 63;
    const int pr = t >> 3, pc = t & 7, qr = j >> 3, qc = j & 7;
    const int ridx = (pr - qr + 7) * 15 + (pc - qc + 7);
    const float v = tab[ridx * 6 + h];
    const float scale = __expf(fminf(logit_scale[h], 4.6051701859880914f));
    rpb[idx] = 16.0f / (1.0f + expf(-v)) - scale - 16.0f;
}

// ---------------- MFMA attention ----------------
// one wave per (window, head); 4 waves/block; all LDS wave-private (no barriers).
// Raw bf16 Q/K frags feed QK^T directly; cosine norms applied to the f32
// accumulator (rnk lane-local, rnq via 16 shfls). Softmax uses a constant
// shift C=scale+16 (pre-folded into rpb) instead of a row-max pass.
__global__ __launch_bounds__(256, 2)
void attn_mfma(const bf16* __restrict__ QKV, const float* __restrict__ rpb,
               const float* __restrict__ logit_scale, bf16* __restrict__ Ctx)
{
    __shared__ __align__(16) char lds[4][9216];
    const int wave = threadIdx.x >> 6, lane = threadIdx.x & 63;
    const int l15 = lane & 15, quad = lane >> 4;
    const int wh = blockIdx.x * 4 + wave;
    const int w = wh / 6, h = wh - w * 6;
    char* Pb = lds[wave];            // 64 rows x 36 bf16 (P halves, then ctx)
    char* Vt = lds[wave] + 4608;     // 32 rows x 72 bf16 (V transposed)

    const bf16* wbase = QKV + (size_t)w * 64 * 576;

    // ---- stage V^T: lane = token, writes its column (2 lanes/bank: free) ----
    {
        const bf16* vp = wbase + (size_t)lane * 576 + 384 + h * 32;
        const short8 v0 = *(const short8*)(vp);
        const short8 v1 = *(const short8*)(vp + 8);
        const short8 v2 = *(const short8*)(vp + 16);
        const short8 v3 = *(const short8*)(vp + 24);
#pragma unroll
        for (int j = 0; j < 8; ++j) {
            *(short*)(Vt + ((j     ) * 72 + lane) * 2) = v0[j];
            *(short*)(Vt + ((j +  8) * 72 + lane) * 2) = v1[j];
            *(short*)(Vt + ((j + 16) * 72 + lane) * 2) = v2[j];
            *(short*)(Vt + ((j + 24) * 72 + lane) * 2) = v3[j];
        }
    }

    // ---- region ids (mask only matters on last window row/col) ----
    const int wr = w / 48, wc = w - wr * 48;
    const bool edge = (wr == 47) || (wc == 47);
    int rid_j[4];
    if (edge) {
#pragma unroll
        for (int jt = 0; jt < 4; ++jt) {
            const int t = jt * 16 + l15;
            const int rr = (wr == 47) ? (((t >> 3) < 4) ? 1 : 2) : 0;
            const int rc = (wc == 47) ? (((t & 7) < 4) ? 1 : 2) : 0;
            rid_j[jt] = rr * 3 + rc;
        }
    }

    const float scale = __expf(fminf(logit_scale[h], 4.6051701859880914f));

    // ---- K frags (raw bf16) + per-col inverse norms ----
    short8 kfr[4];
    float rnk[4];
#pragma unroll
    for (int jt = 0; jt < 4; ++jt) {
        kfr[jt] = *(const short8*)(wbase + (size_t)(jt * 16 + l15) * 576 + 192 + h * 32 + quad * 8);
        float ss = 0.f;
#pragma unroll
        for (int j = 0; j < 8; ++j) {
            const float f = bu2f((unsigned short)kfr[jt][j]);
            ss = fmaf(f, f, ss);
        }
        ss += __shfl_xor(ss, 16); ss += __shfl_xor(ss, 32);
        rnk[jt] = __builtin_amdgcn_rcpf(fmaxf(__builtin_amdgcn_sqrtf(ss), 1e-12f));
    }

    // ---- S = Q K^T on raw frags; per-row inverse norms (scale folded) ----
    floatx4 acc[4][4];
    float rnq[4];
#pragma unroll
    for (int it = 0; it < 4; ++it)
#pragma unroll
        for (int jt = 0; jt < 4; ++jt)
            acc[it][jt] = (floatx4){0.f, 0.f, 0.f, 0.f};
#pragma unroll
    for (int it = 0; it < 4; ++it) {
        const short8 qf = *(const short8*)(wbase + (size_t)(it * 16 + l15) * 576 + h * 32 + quad * 8);
        float ss = 0.f;
#pragma unroll
        for (int j = 0; j < 8; ++j) {
            const float f = bu2f((unsigned short)qf[j]);
            ss = fmaf(f, f, ss);
        }
        ss += __shfl_xor(ss, 16); ss += __shfl_xor(ss, 32);
        rnq[it] = scale * __builtin_amdgcn_rcpf(fmaxf(__builtin_amdgcn_sqrtf(ss), 1e-12f));
#pragma unroll
        for (int jt = 0; jt < 4; ++jt)
            acc[it][jt] = __builtin_amdgcn_mfma_f32_16x16x32_bf16(qf, kfr[jt], acc[it][jt], 0, 0, 0);
    }

    const float* rpbh = rpb + h * 4096;   // already has -(scale+16) folded in

    // ---- normalize + bias + mask + exp + row-sum (no max pass) ----
    float inv[4][4];
#pragma unroll
    for (int it = 0; it < 4; ++it) {
#pragma unroll
        for (int r = 0; r < 4; ++r) {
            const int i = it * 16 + quad * 4 + r;
            const float rq = __shfl(rnq[it], quad * 4 + r);
            int rid_i = 0;
            if (edge) {
                const int rr = (wr == 47) ? (((i >> 3) < 4) ? 1 : 2) : 0;
                const int rc = (wc == 47) ? (((i & 7) < 4) ? 1 : 2) : 0;
                rid_i = rr * 3 + rc;
            }
            float s = 0.f;
#pragma unroll
            for (int jt = 0; jt < 4; ++jt) {
                float v = fmaf(acc[it][jt][r], rq * rnk[jt], rpbh[i * 64 + jt * 16 + l15]);
                if (edge && rid_i != rid_j[jt]) v -= 200.0f;   // mask added twice in ref
                const float e = __expf(v);
                acc[it][jt][r] = e; s += e;
            }
            s += __shfl_xor(s, 1); s += __shfl_xor(s, 2);
            s += __shfl_xor(s, 4); s += __shfl_xor(s, 8);
            inv[it][r] = __builtin_amdgcn_rcpf(s);
        }
    }

    // ---- ctx = P V via LDS round-trip in two 32-key halves ----
    floatx4 ctx[4][2];
#pragma unroll
    for (int it = 0; it < 4; ++it)
#pragma unroll
        for (int dt = 0; dt < 2; ++dt)
            ctx[it][dt] = (floatx4){0.f, 0.f, 0.f, 0.f};

#pragma unroll
    for (int ks = 0; ks < 2; ++ks) {
#pragma unroll
        for (int it = 0; it < 4; ++it)
#pragma unroll
            for (int r = 0; r < 4; ++r) {
                const int i = it * 16 + quad * 4 + r;
                const u32 pk = cvt_pk_bf16(acc[it][ks * 2][r], acc[it][ks * 2 + 1][r]);
                *(short*)(Pb + (i * 36 + l15) * 2)      = (short)pk;
                *(short*)(Pb + (i * 36 + 16 + l15) * 2) = (short)(pk >> 16);
            }
#pragma unroll
        for (int it = 0; it < 4; ++it) {
            const short8 pf = *(const short8*)(Pb + ((it * 16 + l15) * 36 + quad * 8) * 2);
#pragma unroll
            for (int dt = 0; dt < 2; ++dt) {
                const short8 vf = *(const short8*)(Vt + ((dt * 16 + l15) * 72 + ks * 32 + quad * 8) * 2);
                ctx[it][dt] = __builtin_amdgcn_mfma_f32_16x16x32_bf16(pf, vf, ctx[it][dt], 0, 0, 0);
            }
        }
    }

    // ---- ctx/sum -> LDS (reuse Pb; same-wave order keeps it race-free) ----
#pragma unroll
    for (int it = 0; it < 4; ++it)
#pragma unroll
        for (int r = 0; r < 4; ++r) {
            const int i = it * 16 + quad * 4 + r;
            const u32 pk = cvt_pk_bf16(ctx[it][0][r] * inv[it][r], ctx[it][1][r] * inv[it][r]);
            *(short*)(Pb + (i * 36 + l15) * 2)      = (short)pk;
            *(short*)(Pb + (i * 36 + 16 + l15) * 2) = (short)(pk >> 16);
        }

    // ---- packed-A-layout store for proj GEMM ----
    const int tok = w * 64 + lane;
    const size_t obase = ((size_t)(tok >> 4) * 24 + h * 4) * 128 + (size_t)(tok & 15) * 8;
#pragma unroll
    for (int c = 0; c < 4; ++c) {
        const short8 row = *(const short8*)(Pb + (lane * 36 + c * 8) * 2);
        *(short8*)(Ctx + obase + (size_t)c * 128) = row;
    }
}

// ---------------- LN kernels (vectorized: 2 tokens/wave, 8 ch/lane) ----------------
// 192 ch = 24 lanes x bf16x8. Lanes 0-23 of each 32-lane half own one token;
// reductions are shfl_xor width-32. Hpk packing falls directly out of the
// registers (lane kg holds one k-group) -> no LDS, no barriers.

__global__ __launch_bounds__(256)
void ln_h(const bf16* __restrict__ X, const float* __restrict__ hidden,
          const float* __restrict__ g, const float* __restrict__ b,
          bf16* __restrict__ Hres, bf16* __restrict__ Hpk)
{
    const int wv = threadIdx.x >> 6;
    const int lane = threadIdx.x & 63;
    const int half = lane >> 5, sl = lane & 31;
    const int tok = blockIdx.x * 8 + wv * 2 + half;
    const int kg = sl;                         // 0..23 active
    const bool act = kg < 24;

    float f[8];
    if (act) {
        const short8 xv = *(const short8*)(X + (size_t)tok * 192 + kg * 8);
#pragma unroll
        for (int j = 0; j < 8; ++j) f[j] = bu2f((unsigned short)xv[j]);
    } else {
#pragma unroll
        for (int j = 0; j < 8; ++j) f[j] = 0.0f;
    }
    float s = 0.f;
#pragma unroll
    for (int j = 0; j < 8; ++j) s += f[j];
#pragma unroll
    for (int o = 16; o > 0; o >>= 1) s += __shfl_xor(s, o, 32);
    const float mean = s * (1.0f / 192.0f);
    float d[8], vsum = 0.f;
#pragma unroll
    for (int j = 0; j < 8; ++j) { d[j] = f[j] - mean; vsum = fmaf(d[j], d[j], vsum); }
    if (!act) vsum = 0.f;
#pragma unroll
    for (int o = 16; o > 0; o >>= 1) vsum += __shfl_xor(vsum, o, 32);
    const float rstd = rsqrtf(vsum * (1.0f / 192.0f) + 1e-5f);

    if (act) {
        const int grow = gather_row(tok);
        const float* hr = hidden + (size_t)grow * 192 + kg * 8;
        const float4 h0 = *(const float4*)hr;
        const float4 h1 = *(const float4*)(hr + 4);
        const float4 g0 = *(const float4*)(g + kg * 8);
        const float4 g1 = *(const float4*)(g + kg * 8 + 4);
        const float4 b0 = *(const float4*)(b + kg * 8);
        const float4 b1 = *(const float4*)(b + kg * 8 + 4);
        float hv[8];
        hv[0] = h0.x + d[0] * rstd * g0.x + b0.x;
        hv[1] = h0.y + d[1] * rstd * g0.y + b0.y;
        hv[2] = h0.z + d[2] * rstd * g0.z + b0.z;
        hv[3] = h0.w + d[3] * rstd * g0.w + b0.w;
        hv[4] = h1.x + d[4] * rstd * g1.x + b1.x;
        hv[5] = h1.y + d[5] * rstd * g1.y + b1.y;
        hv[6] = h1.z + d[6] * rstd * g1.z + b1.z;
        hv[7] = h1.w + d[7] * rstd * g1.w + b1.w;
        short8 o;
#pragma unroll
        for (int j = 0; j < 8; ++j) o[j] = (short)f2bu(hv[j]);
        *(short8*)(Hres + (size_t)tok * 192 + kg * 8) = o;
        const int mtG = tok >> 4, mm = tok & 15;
        *(short8*)(Hpk + ((size_t)(mtG * 24 + kg) * 16 + mm) * 8) = o;
    }
}

__global__ __launch_bounds__(256)
void ln_out(const bf16* __restrict__ Y, const bf16* __restrict__ Hres,
            const float* __restrict__ g, const float* __restrict__ b,
            float* __restrict__ Out)
{
    const int wv = threadIdx.x >> 6;
    const int lane = threadIdx.x & 63;
    const int half = lane >> 5, sl = lane & 31;
    const int tok = blockIdx.x * 8 + wv * 2 + half;
    const int kg = sl;
    const bool act = kg < 24;

    float f[8];
    if (act) {
        const short8 yv = *(const short8*)(Y + (size_t)tok * 192 + kg * 8);
#pragma unroll
        for (int j = 0; j < 8; ++j) f[j] = bu2f((unsigned short)yv[j]);
    } else {
#pragma unroll
        for (int j = 0; j < 8; ++j) f[j] = 0.0f;
    }
    float s = 0.f;
#pragma unroll
    for (int j = 0; j < 8; ++j) s += f[j];
#pragma unroll
    for (int o = 16; o > 0; o >>= 1) s += __shfl_xor(s, o, 32);
    const float mean = s * (1.0f / 192.0f);
    float d[8], vsum = 0.f;
#pragma unroll
    for (int j = 0; j < 8; ++j) { d[j] = f[j] - mean; vsum = fmaf(d[j], d[j], vsum); }
    if (!act) vsum = 0.f;
#pragma unroll
    for (int o = 16; o > 0; o >>= 1) vsum += __shfl_xor(vsum, o, 32);
    const float rstd = rsqrtf(vsum * (1.0f / 192.0f) + 1e-5f);

    if (act) {
        const short8 hv = *(const short8*)(Hres + (size_t)tok * 192 + kg * 8);
        const float4 g0 = *(const float4*)(g + kg * 8);
        const float4 g1 = *(const float4*)(g + kg * 8 + 4);
        const float4 b0 = *(const float4*)(b + kg * 8);
        const float4 b1 = *(const float4*)(b + kg * 8 + 4);
        const int grow = gather_row(tok);
        float* op = Out + (size_t)grow * 192 + kg * 8;
        float4 o0, o1;
        o0.x = bu2f((unsigned short)hv[0]) + d[0] * rstd * g0.x + b0.x;
        o0.y = bu2f((unsigned short)hv[1]) + d[1] * rstd * g0.y + b0.y;
        o0.z = bu2f((unsigned short)hv[2]) + d[2] * rstd * g0.z + b0.z;
        o0.w = bu2f((unsigned short)hv[3]) + d[3] * rstd * g0.w + b0.w;
        o1.x = bu2f((unsigned short)hv[4]) + d[4] * rstd * g1.x + b1.x;
        o1.y = bu2f((unsigned short)hv[5]) + d[5] * rstd * g1.y + b1.y;
        o1.z = bu2f((unsigned short)hv[6]) + d[6] * rstd * g1.z + b1.z;
        o1.w = bu2f((unsigned short)hv[7]) + d[7] * rstd * g1.w + b1.w;
        *(float4*)op = o0;
        *(float4*)(op + 4) = o1;
    }
}

// ---------------- launch ----------------

extern "C" void kernel_launch(void* const* d_in, const int* in_sizes, int n_in,
                              void* d_out, int out_size, void* d_ws, size_t ws_size,
                              hipStream_t stream)
{
    const float* hidden = (const float*)d_in[0];
    const float* q_w = (const float*)d_in[1];
    const float* q_b = (const float*)d_in[2];
    const float* k_w = (const float*)d_in[3];
    const float* v_w = (const float*)d_in[4];
    const float* v_b = (const float*)d_in[5];
    const float* logit_scale = (const float*)d_in[6];
    const float* cpb_w1 = (const float*)d_in[7];
    const float* cpb_b1 = (const float*)d_in[8];
    const float* cpb_w2 = (const float*)d_in[9];
    const float* proj_w = (const float*)d_in[10];
    const float* proj_b = (const float*)d_in[11];
    const float* ln1_g = (const float*)d_in[12];
    const float* ln1_b = (const float*)d_in[13];
    const float* fc1_w = (const float*)d_in[14];
    const float* fc1_b = (const float*)d_in[15];
    const float* fc2_w = (const float*)d_in[16];
    const float* fc2_b = (const float*)d_in[17];
    const float* ln2_g = (const float*)d_in[18];
    const float* ln2_b = (const float*)d_in[19];

    char* ws = (char*)d_ws;
    bf16*  APK   = (bf16*)(ws + 0);
    float* RPB   = (float*)(ws + 0);
    bf16*  PROJW = (bf16*)(ws + (1 << 20));
    bf16*  MID   = (bf16*)(ws + 0);
    bf16*  CTX   = (bf16*)(ws + 56623104);
    bf16*  QKVW  = (bf16*)(ws + 56623104);
    float* QKVB  = (float*)(ws + 56844288);
    float* TAB   = (float*)(ws + 56846592);
    bf16*  QKV   = (bf16*)(ws + 113246208);
    bf16*  HRES  = (bf16*)(ws + 113246208);
    bf16*  HPK   = (bf16*)(ws + 169869312);
    bf16*  Y     = (bf16*)(ws + 226492416);
    bf16*  X     = (bf16*)(ws + 283115520);
    bf16*  FC1W  = (bf16*)(ws + 283115520);
    bf16*  FC2W  = (bf16*)(ws + 283262976);
    float* OUT   = (float*)d_out;

    cpb_mlp<<<225, 512, 0, stream>>>(cpb_w1, cpb_b1, cpb_w2, TAB);
    fuse_bias<<<3, 256, 0, stream>>>(q_b, v_b, QKVB);
    pack_w<<<18, 256, 0, stream>>>(q_w, QKVW,                 192, 192);
    pack_w<<<18, 256, 0, stream>>>(k_w, QKVW + 12 * 24 * 128, 192, 192);
    pack_w<<<18, 256, 0, stream>>>(v_w, QKVW + 24 * 24 * 128, 192, 192);
    conv_pack<<<13824, 256, 0, stream>>>(hidden, APK);

    // QKV: K=192, N=576 (9 slabs), strip=288 rows -> 9*512/4 = 1152 blocks
    gemm_rs<192, 4, 18, false, EPI_NONE, 1, 3><<<1152, 256, 0, stream>>>(APK, QKVW, QKVB, QKV, 576);

    rpb_expand<<<96, 256, 0, stream>>>(TAB, logit_scale, RPB);
    pack_w<<<18, 256, 0, stream>>>(proj_w, PROJW, 192, 192);

    attn_mfma<<<3456, 256, 0, stream>>>(QKV, RPB, logit_scale, CTX);

    // proj: K=192, N=192 (3 slabs), strip=144 rows -> 3*1024/4 = 768 blocks
    gemm_rs<192, 4, 9, false, EPI_NONE, 1, 3><<<768, 256, 0, stream>>>(CTX, PROJW, proj_b, X, 192);

    ln_h<<<NTOK / 8, 256, 0, stream>>>(X, hidden, ln1_g, ln1_b, HRES, HPK);

    pack_w<<<36, 256, 0, stream>>>(fc1_w, FC1W, 192, 384);
    pack_w<<<36, 256, 0, stream>>>(fc2_w, FC2W, 384, 192);

    // fc1: K=192, N=384 (6 slabs), packed out (KGOUT=48) -> 6*512/4 = 768 blocks
    gemm_rs<192, 4, 18, true, EPI_GELU, 48, 3><<<768, 256, 0, stream>>>(HPK, FC1W, fc1_b, MID, 384);
    // fc2: K=384, N=192, NT=2 (6 slabs of 32) -> 6*512/4 = 768 blocks
    gemm_rs<384, 2, 18, false, EPI_NONE, 1, 2><<<768, 256, 0, stream>>>(MID, FC2W, fc2_b, Y, 192);

    ln_out<<<NTOK / 8, 256, 0, stream>>>(Y, HRES, ln2_g, ln2_b, OUT);
}